// Round 5
// baseline (360.170 us; speedup 1.0000x reference)
//
#include <hip/hip_runtime.h>
#include <hip/hip_bf16.h>

#define N_NODES 50000
#define N_EDGES 800000
#define D_IN    128
#define D_H     64
#define SZ_C    4
#define D_ALL   (SZ_C * D_H)   // 256

typedef __bf16 bf16x8 __attribute__((ext_vector_type(8)));
typedef float  f32x4  __attribute__((ext_vector_type(4)));
typedef unsigned short us8 __attribute__((ext_vector_type(8)));

__device__ __forceinline__ float bf2f(unsigned short u) {
    return __uint_as_float(((unsigned)u) << 16);
}
__device__ __forceinline__ unsigned short f2bf(float f) {
    unsigned u = __float_as_uint(f);
    unsigned r = (u + 0x7fffu + ((u >> 16) & 1u)) >> 16;   // round-to-nearest-even
    return (unsigned short)r;
}

// ---------------- setup kernels ----------------

// deg starts at 1: reserves the self-loop slot in each CSR row AND matches
// reference deg = in_deg + 1.
__global__ void init_deg_kernel(int* __restrict__ deg_cnt, int* __restrict__ cursor, int n) {
    int i = blockIdx.x * blockDim.x + threadIdx.x;
    if (i < n) { deg_cnt[i] = 1; cursor[i] = 0; }
}

__global__ void hist_kernel(const int* __restrict__ dst, int* __restrict__ deg_cnt, int e) {
    int i = blockIdx.x * blockDim.x + threadIdx.x;
    if (i < e) atomicAdd(&deg_cnt[dst[i]], 1);
}

__global__ void dinv_kernel(const int* __restrict__ deg_cnt, float* __restrict__ dinv, int n) {
    int i = blockIdx.x * blockDim.x + threadIdx.x;
    if (i < n) dinv[i] = rsqrtf((float)deg_cnt[i]);
}

// ---- 3-phase scan: partial per-block inclusive scan -> scan block sums -> add ----

__global__ __launch_bounds__(1024) void scan_block_kernel(
    const int* __restrict__ cnt, int* __restrict__ row_start, int* __restrict__ bsum, int n) {
    __shared__ int wsum[16];
    int t = threadIdx.x;
    int lane = t & 63, wv = t >> 6;
    int base = blockIdx.x * 1024;
    int v = (base + t < n) ? cnt[base + t] : 0;
    int x = v;
    #pragma unroll
    for (int off = 1; off < 64; off <<= 1) {
        int y = __shfl_up(x, off, 64);
        if (lane >= off) x += y;
    }
    if (lane == 63) wsum[wv] = x;
    __syncthreads();
    if (wv == 0 && lane < 16) {
        int ws = wsum[lane];
        #pragma unroll
        for (int off = 1; off < 16; off <<= 1) {
            int y = __shfl_up(ws, off, 64);
            if (lane >= off) ws += y;
        }
        wsum[lane] = ws;
    }
    __syncthreads();
    int wbase = (wv == 0) ? 0 : wsum[wv - 1];
    int incl = x + wbase;
    if (base + t < n) row_start[base + t + 1] = incl;
    if (t == 1023) bsum[blockIdx.x] = incl;   // padded lanes add 0 -> block total
}

__global__ void scan_tot_kernel(int* __restrict__ bsum, int nb) {
    int lane = threadIdx.x;   // one wave (64 >= nb)
    int v = (lane < nb) ? bsum[lane] : 0;
    int x = v;
    #pragma unroll
    for (int off = 1; off < 64; off <<= 1) {
        int y = __shfl_up(x, off, 64);
        if (lane >= off) x += y;
    }
    if (lane < nb) bsum[lane] = x - v;   // exclusive
}

__global__ __launch_bounds__(1024) void scan_add_kernel(
    const int* __restrict__ bsum, int* __restrict__ row_start, int n) {
    int b = blockIdx.x, t = threadIdx.x;
    int i = b * 1024 + t;
    if (b == 0 && t == 0) row_start[0] = 0;
    if (i < n) row_start[i + 1] += bsum[b];
}

__global__ void csr_build_kernel(const int* __restrict__ src, const int* __restrict__ dst,
                                 const int* __restrict__ row_start, int* __restrict__ cursor,
                                 const float* __restrict__ dinv,
                                 int2* __restrict__ csr_ec, int e) {
    int i = blockIdx.x * blockDim.x + threadIdx.x;
    if (i < e) {
        int d = dst[i];
        int s = src[i];
        int pos = row_start[d] + atomicAdd(&cursor[d], 1);
        int2 rec;
        rec.x = s;
        rec.y = __float_as_int(dinv[s] * dinv[d]);
        csr_ec[pos] = rec;
    }
}

// self edge in the last (reserved) slot of each row: coef = dinv^2
__global__ void self_edge_kernel(const int* __restrict__ row_start, const float* __restrict__ dinv,
                                 int2* __restrict__ csr_ec, int n) {
    int i = blockIdx.x * blockDim.x + threadIdx.x;
    if (i < n) {
        float dv = dinv[i];
        int2 rec;
        rec.x = i;
        rec.y = __float_as_int(dv * dv);
        csr_ec[row_start[i + 1] - 1] = rec;
    }
}

// fp32 -> bf16 elementwise (n multiple of 4)
__global__ void f2bf_kernel(const float* __restrict__ in, unsigned short* __restrict__ out, int n4) {
    int i = blockIdx.x * blockDim.x + threadIdx.x;
    if (i < n4) {
        float4 v = ((const float4*)in)[i];
        ushort4 o;
        o.x = f2bf(v.x); o.y = f2bf(v.y); o.z = f2bf(v.z); o.w = f2bf(v.w);
        ((ushort4*)out)[i] = o;
    }
}

// Pack weight W [4ch][K][64] (fp32, channel stride chanStride) into MFMA B-frag layout:
// P[((c*ksteps + ks)*4 + n)*512 + lane*8 + j] = bf16(W[c][ks*32 + (lane>>4)*8 + j][n*16 + (lane&15)])
__global__ void pack_b_kernel(const float* __restrict__ W, int chanStride, int ksteps,
                              unsigned short* __restrict__ P, int total) {
    int tid = blockIdx.x * blockDim.x + threadIdx.x;
    if (tid >= total) return;
    int j = tid & 7;
    int lane = (tid >> 3) & 63;
    int n = (tid >> 9) & 3;
    int cks = tid >> 11;
    int ks = cks % ksteps;
    int c = cks / ksteps;
    int k = ks * 32 + (lane >> 4) * 8 + j;
    int d = n * 16 + (lane & 15);
    P[tid] = f2bf(W[(size_t)c * chanStride + (size_t)k * 64 + d]);
}

// ---------------- aggregation: z[i] = sum_j coef_j * h[src_j] (self edge in CSR) ----
// 64-dim column slices (blockIdx.y): gather working set per slice = N*128B = 6.4 MB,
// ~L2-resident. One wave per node x slice; lane = (edge group g 0..7, sublane sl 0..7);
// lane loads 16 B (8 bf16 dims); 8 edges/instr, x2 unroll = 16 edges in flight.

template<int RS>   // row stride in elems (128 for x, 256 for h)
__global__ __launch_bounds__(256) void agg64_kernel(
    const unsigned short* __restrict__ h,   // bf16 [N, RS]
    const int* __restrict__ row_start,
    const int2* __restrict__ csr_ec,
    unsigned short* __restrict__ z)         // bf16 [N, RS]
{
    int w = threadIdx.x >> 6;
    int lane = threadIdx.x & 63;
    int i = blockIdx.x * 4 + w;
    int colOff = blockIdx.y * 64;
    int g = lane >> 3;          // edge group
    int sl = lane & 7;          // dim sublane
    int s = row_start[i], e = row_start[i + 1];
    float acc[8] = {};
    const unsigned short* hb = h + colOff + sl * 8;
    for (int j0 = s; j0 < e; j0 += 16) {
        int ja = j0 + g, jb = j0 + 8 + g;
        int2 ea = (ja < e) ? csr_ec[ja] : make_int2(0, 0);
        int2 eb = (jb < e) ? csr_ec[jb] : make_int2(0, 0);
        us8 ua = *(const us8*)(hb + (size_t)ea.x * RS);
        us8 ub = *(const us8*)(hb + (size_t)eb.x * RS);
        float ca = __int_as_float(ea.y), cb = __int_as_float(eb.y);
        #pragma unroll
        for (int q = 0; q < 8; ++q)
            acc[q] += ca * bf2f(ua[q]) + cb * bf2f(ub[q]);
    }
    // butterfly-combine across the 8 edge groups
    #pragma unroll
    for (int off = 8; off < 64; off <<= 1)
        #pragma unroll
        for (int q = 0; q < 8; ++q)
            acc[q] += __shfl_xor(acc[q], off, 64);
    if (g == 0) {
        us8 o;
        #pragma unroll
        for (int q = 0; q < 8; ++q) o[q] = f2bf(acc[q]);
        *(us8*)(z + (size_t)i * RS + colOff + sl * 8) = o;
    }
}

// ---------------- MFMA GEMM + fused epilogue ----------------
// h' = relu(z@W + b) + (z@W + b); EPI=0: write bf16 h'; EPI=1: LayerNorm -> fp32 out
// grid: (ceil(M/64), 4 channels), block 256 = 4 waves; wave w -> rows m0+16w..+15.

template<int EPI>
__global__ __launch_bounds__(256) void mfma_gemm_kernel(
    const unsigned short* __restrict__ A, int lda, int aChanOff,
    const unsigned short* __restrict__ Bpack, int ksteps,
    const float* __restrict__ bias, int biasChanStride,
    unsigned short* __restrict__ Cbf,
    float* __restrict__ outF, const float* __restrict__ gamma, const float* __restrict__ beta,
    int M)
{
    int c = blockIdx.y;
    int m0 = blockIdx.x * 64;
    int w = threadIdx.x >> 6, lane = threadIdx.x & 63;
    int arow = m0 + w * 16 + (lane & 15);
    int arow_c = (arow < M) ? arow : (M - 1);   // clamp: bad rows only feed guarded stores
    const unsigned short* Ap = A + (size_t)arow_c * lda + aChanOff * c + (lane >> 4) * 8;
    const unsigned short* Bp = Bpack + ((size_t)c * ksteps * 4) * 512 + (size_t)lane * 8;
    f32x4 acc[4] = {};
    for (int ks = 0; ks < ksteps; ++ks) {
        bf16x8 af = *(const bf16x8*)(Ap + ks * 32);
        const unsigned short* b = Bp + (size_t)ks * 2048;
        #pragma unroll
        for (int n = 0; n < 4; ++n) {
            bf16x8 bfr = *(const bf16x8*)(b + n * 512);
            acc[n] = __builtin_amdgcn_mfma_f32_16x16x32_bf16(af, bfr, acc[n], 0, 0, 0);
        }
    }
    int col = lane & 15;
    int rbase = m0 + w * 16 + (lane >> 4) * 4;
    float hv[4][4];
    #pragma unroll
    for (int n = 0; n < 4; ++n) {
        float bv = bias[c * biasChanStride + n * 16 + col];
        #pragma unroll
        for (int r = 0; r < 4; ++r) {
            float a = acc[n][r] + bv;
            hv[n][r] = (a > 0.f) ? a + a : a;   // relu(a) + a
        }
    }
    if (EPI == 0) {
        #pragma unroll
        for (int n = 0; n < 4; ++n) {
            #pragma unroll
            for (int r = 0; r < 4; ++r) {
                int rr = rbase + r;
                if (rr < M) Cbf[(size_t)rr * D_ALL + c * 64 + n * 16 + col] = f2bf(hv[n][r]);
            }
        }
    } else {
        float sum[4], sq[4];
        #pragma unroll
        for (int r = 0; r < 4; ++r) {
            sum[r] = hv[0][r] + hv[1][r] + hv[2][r] + hv[3][r];
            sq[r] = hv[0][r]*hv[0][r] + hv[1][r]*hv[1][r] + hv[2][r]*hv[2][r] + hv[3][r]*hv[3][r];
        }
        #pragma unroll
        for (int off = 1; off < 16; off <<= 1) {
            #pragma unroll
            for (int r = 0; r < 4; ++r) {
                sum[r] += __shfl_xor(sum[r], off, 64);
                sq[r]  += __shfl_xor(sq[r], off, 64);
            }
        }
        float mu[4], rinv[4];
        #pragma unroll
        for (int r = 0; r < 4; ++r) {
            mu[r] = sum[r] * (1.f / 64.f);
            float var = sq[r] * (1.f / 64.f) - mu[r] * mu[r];
            rinv[r] = rsqrtf(var + 1e-6f);
        }
        #pragma unroll
        for (int n = 0; n < 4; ++n) {
            float gv = gamma[n * 16 + col];
            float bv2 = beta[n * 16 + col];
            #pragma unroll
            for (int r = 0; r < 4; ++r) {
                int rr = rbase + r;
                if (rr < M)
                    outF[(size_t)c * N_NODES * D_H + (size_t)rr * D_H + n * 16 + col] =
                        (hv[n][r] - mu[r]) * rinv[r] * gv + bv2;
            }
        }
    }
}

// ---------------- launch ----------------

extern "C" void kernel_launch(void* const* d_in, const int* in_sizes, int n_in,
                              void* d_out, int out_size, void* d_ws, size_t ws_size,
                              hipStream_t stream) {
    const float* x     = (const float*)d_in[0];
    const int*   edge  = (const int*)d_in[1];
    const float* W0    = (const float*)d_in[3];
    const float* b0    = (const float*)d_in[4];
    const float* Wl    = (const float*)d_in[5];
    const float* bl    = (const float*)d_in[6];
    const float* gamma = (const float*)d_in[7];
    const float* beta  = (const float*)d_in[8];
    float* out = (float*)d_out;

    const int* e_src = edge;            // edge[0]
    const int* e_dst = edge + N_EDGES;  // edge[1]

    char* ws = (char*)d_ws;
    size_t off = 0;
    auto alloc = [&](size_t bytes) -> void* {
        void* p = ws + off;
        off = (off + bytes + 255) & ~(size_t)255;
        return p;
    };
    const int NE_TOT = N_EDGES + N_NODES;   // real edges + self loops
    const int NB_SCAN = (N_NODES + 1023) / 1024;   // 49
    int*   deg_cnt   = (int*)  alloc(sizeof(int)   * N_NODES);
    int*   cursor    = (int*)  alloc(sizeof(int)   * N_NODES);
    int*   row_start = (int*)  alloc(sizeof(int)   * (N_NODES + 1));
    int*   bsum      = (int*)  alloc(sizeof(int)   * 64);
    float* dinv      = (float*)alloc(sizeof(float) * N_NODES);
    int2*  csr_ec    = (int2*) alloc(sizeof(int2)  * NE_TOT);
    unsigned short* x_bf  = (unsigned short*)alloc(sizeof(unsigned short) * (size_t)N_NODES * D_IN);
    unsigned short* W0p   = (unsigned short*)alloc(sizeof(unsigned short) * SZ_C * 4 * 4 * 512);
    unsigned short* Wl0p  = (unsigned short*)alloc(sizeof(unsigned short) * SZ_C * 2 * 4 * 512);
    unsigned short* Wl1p  = (unsigned short*)alloc(sizeof(unsigned short) * SZ_C * 2 * 4 * 512);
    unsigned short* zbuf  = (unsigned short*)alloc(sizeof(unsigned short) * (size_t)N_NODES * D_ALL);
    unsigned short* h_bf  = (unsigned short*)alloc(sizeof(unsigned short) * (size_t)N_NODES * D_ALL);

    const int nb_n = (N_NODES + 255) / 256;
    const int nb_e = (N_EDGES + 255) / 256;

    init_deg_kernel<<<nb_n, 256, 0, stream>>>(deg_cnt, cursor, N_NODES);
    hist_kernel<<<nb_e, 256, 0, stream>>>(e_dst, deg_cnt, N_EDGES);
    dinv_kernel<<<nb_n, 256, 0, stream>>>(deg_cnt, dinv, N_NODES);
    scan_block_kernel<<<NB_SCAN, 1024, 0, stream>>>(deg_cnt, row_start, bsum, N_NODES);
    scan_tot_kernel<<<1, 64, 0, stream>>>(bsum, NB_SCAN);
    scan_add_kernel<<<NB_SCAN, 1024, 0, stream>>>(bsum, row_start, N_NODES);
    csr_build_kernel<<<nb_e, 256, 0, stream>>>(e_src, e_dst, row_start, cursor, dinv,
                                               csr_ec, N_EDGES);
    self_edge_kernel<<<nb_n, 256, 0, stream>>>(row_start, dinv, csr_ec, N_NODES);
    // weight packing + x conversion
    pack_b_kernel<<<(SZ_C * 4 * 4 * 512 + 255) / 256, 256, 0, stream>>>(
        W0, D_IN * D_H, 4, W0p, SZ_C * 4 * 4 * 512);
    pack_b_kernel<<<(SZ_C * 2 * 4 * 512 + 255) / 256, 256, 0, stream>>>(
        Wl, 2 * D_H * D_H, 2, Wl0p, SZ_C * 2 * 4 * 512);
    pack_b_kernel<<<(SZ_C * 2 * 4 * 512 + 255) / 256, 256, 0, stream>>>(
        Wl + D_H * D_H, 2 * D_H * D_H, 2, Wl1p, SZ_C * 2 * 4 * 512);
    f2bf_kernel<<<((N_NODES * D_IN / 4) + 255) / 256, 256, 0, stream>>>(
        x, x_bf, N_NODES * D_IN / 4);

    dim3 ggrid((N_NODES + 63) / 64, SZ_C);
    dim3 agrid128(N_NODES / 4, 2);   // 2 x 64-wide slices
    dim3 agrid256(N_NODES / 4, 4);   // 4 x 64-wide slices

    // layer 0: z = agg(x_bf) [N,128]; h = relures(z@W0 + b0) [N,256]
    agg64_kernel<D_IN><<<agrid128, 256, 0, stream>>>(x_bf, row_start, csr_ec, zbuf);
    mfma_gemm_kernel<0><<<ggrid, 256, 0, stream>>>(zbuf, D_IN, 0, W0p, 4,
                                                   b0, 64, h_bf, nullptr, nullptr, nullptr, N_NODES);
    // layer 1: z = agg(h) [N,256]; h = relures(z@Wl0 + bl0)
    agg64_kernel<D_ALL><<<agrid256, 256, 0, stream>>>(h_bf, row_start, csr_ec, zbuf);
    mfma_gemm_kernel<0><<<ggrid, 256, 0, stream>>>(zbuf, D_ALL, 64, Wl0p, 2,
                                                   bl, 2 * 64, h_bf, nullptr, nullptr, nullptr, N_NODES);
    // layer 2: z = agg(h); out = LN(relures(z@Wl1 + bl1)) -> d_out fp32
    agg64_kernel<D_ALL><<<agrid256, 256, 0, stream>>>(h_bf, row_start, csr_ec, zbuf);
    mfma_gemm_kernel<1><<<ggrid, 256, 0, stream>>>(zbuf, D_ALL, 64, Wl1p, 2,
                                                   bl + 64, 2 * 64, nullptr, out, gamma, beta, N_NODES);
}

// Round 6
// 313.845 us; speedup vs baseline: 1.1476x; 1.1476x over previous
//
#include <hip/hip_runtime.h>
#include <hip/hip_bf16.h>

#define N_NODES 50000
#define N_EDGES 800000
#define D_IN    128
#define D_H     64
#define SZ_C    4
#define D_ALL   (SZ_C * D_H)   // 256

typedef __bf16 bf16x8 __attribute__((ext_vector_type(8)));
typedef __bf16 bf16x2 __attribute__((ext_vector_type(2)));
typedef float  f32x4  __attribute__((ext_vector_type(4)));
typedef unsigned short us8 __attribute__((ext_vector_type(8)));

#if defined(__has_builtin)
#if __has_builtin(__builtin_amdgcn_fdot2_f32_bf16)
#define HAVE_DOT2 1
#else
#define HAVE_DOT2 0
#endif
#else
#define HAVE_DOT2 0
#endif

__device__ __forceinline__ float bf2f(unsigned short u) {
    return __uint_as_float(((unsigned)u) << 16);
}
__device__ __forceinline__ unsigned short f2bf(float f) {
    unsigned u = __float_as_uint(f);
    unsigned r = (u + 0x7fffu + ((u >> 16) & 1u)) >> 16;   // round-to-nearest-even
    return (unsigned short)r;
}

// acc += a.lo*c.lo + a.hi*c.hi, all bf16 pairs packed in u32, f32 accumulate
__device__ __forceinline__ float dot2bf(unsigned ab, unsigned cc, float acc) {
#if HAVE_DOT2
    return __builtin_amdgcn_fdot2_f32_bf16(__builtin_bit_cast(bf16x2, ab),
                                           __builtin_bit_cast(bf16x2, cc), acc, false);
#else
    float a0 = __uint_as_float(ab << 16);
    float a1 = __uint_as_float(ab & 0xffff0000u);
    float c0 = __uint_as_float(cc << 16);
    float c1 = __uint_as_float(cc & 0xffff0000u);
    return acc + a0 * c0 + a1 * c1;
#endif
}

// ---------------- setup kernels ----------------

// deg starts at 1: self-loop slot; matches reference deg = in_deg + 1.
__global__ void init_deg_kernel(int* __restrict__ deg_cnt, int* __restrict__ cursor, int n) {
    int i = blockIdx.x * blockDim.x + threadIdx.x;
    if (i < n) { deg_cnt[i] = 1; cursor[i] = 0; }
}

__global__ void hist_kernel(const int* __restrict__ dst, int* __restrict__ deg_cnt, int e) {
    int i = blockIdx.x * blockDim.x + threadIdx.x;
    if (i < e) atomicAdd(&deg_cnt[dst[i]], 1);
}

// dinv + padded row length (multiple of 4)
__global__ void dinv_kernel(const int* __restrict__ deg_cnt, float* __restrict__ dinv,
                            int* __restrict__ padlen, int n) {
    int i = blockIdx.x * blockDim.x + threadIdx.x;
    if (i < n) {
        dinv[i] = rsqrtf((float)deg_cnt[i]);
        padlen[i] = (deg_cnt[i] + 3) & ~3;
    }
}

// ---- 3-phase scan over padlen ----

__global__ __launch_bounds__(1024) void scan_block_kernel(
    const int* __restrict__ cnt, int* __restrict__ row_start, int* __restrict__ bsum, int n) {
    __shared__ int wsum[16];
    int t = threadIdx.x;
    int lane = t & 63, wv = t >> 6;
    int base = blockIdx.x * 1024;
    int v = (base + t < n) ? cnt[base + t] : 0;
    int x = v;
    #pragma unroll
    for (int off = 1; off < 64; off <<= 1) {
        int y = __shfl_up(x, off, 64);
        if (lane >= off) x += y;
    }
    if (lane == 63) wsum[wv] = x;
    __syncthreads();
    if (wv == 0 && lane < 16) {
        int ws = wsum[lane];
        #pragma unroll
        for (int off = 1; off < 16; off <<= 1) {
            int y = __shfl_up(ws, off, 64);
            if (lane >= off) ws += y;
        }
        wsum[lane] = ws;
    }
    __syncthreads();
    int wbase = (wv == 0) ? 0 : wsum[wv - 1];
    int incl = x + wbase;
    if (base + t < n) row_start[base + t + 1] = incl;
    if (t == 1023) bsum[blockIdx.x] = incl;
}

__global__ void scan_tot_kernel(int* __restrict__ bsum, int nb) {
    int lane = threadIdx.x;   // one wave
    int v = (lane < nb) ? bsum[lane] : 0;
    int x = v;
    #pragma unroll
    for (int off = 1; off < 64; off <<= 1) {
        int y = __shfl_up(x, off, 64);
        if (lane >= off) x += y;
    }
    if (lane < nb) bsum[lane] = x - v;   // exclusive
}

__global__ __launch_bounds__(1024) void scan_add_kernel(
    const int* __restrict__ bsum, int* __restrict__ row_start, int n) {
    int b = blockIdx.x, t = threadIdx.x;
    int i = b * 1024 + t;
    if (b == 0 && t == 0) row_start[0] = 0;
    if (i < n) row_start[i + 1] += bsum[b];
}

// scatter real edges; record = (src, bf16(coef) in low16)
__global__ void csr_build_kernel(const int* __restrict__ src, const int* __restrict__ dst,
                                 const int* __restrict__ row_start, int* __restrict__ cursor,
                                 const float* __restrict__ dinv,
                                 int2* __restrict__ csr_ec, int e) {
    int i = blockIdx.x * blockDim.x + threadIdx.x;
    if (i < e) {
        int d = dst[i];
        int s = src[i];
        int pos = row_start[d] + atomicAdd(&cursor[d], 1);
        int2 rec;
        rec.x = s;
        rec.y = (int)(unsigned)f2bf(dinv[s] * dinv[d]);
        csr_ec[pos] = rec;
    }
}

// self edge + zero-coef padding up to padded row length
__global__ void self_pad_kernel(const int* __restrict__ row_start, const int* __restrict__ deg_cnt,
                                const float* __restrict__ dinv, int2* __restrict__ csr_ec, int n) {
    int i = blockIdx.x * blockDim.x + threadIdx.x;
    if (i < n) {
        int s = row_start[i], e = row_start[i + 1];
        int selfslot = s + deg_cnt[i] - 1;
        float dv = dinv[i];
        int2 rec;
        rec.x = i;
        rec.y = (int)(unsigned)f2bf(dv * dv);
        csr_ec[selfslot] = rec;
        rec.y = 0;
        for (int k = selfslot + 1; k < e; ++k) csr_ec[k] = rec;
    }
}

// 16 (0,0) records past the end: safe over-read target for unrolled tails
__global__ void end_pad_kernel(const int* __restrict__ row_start, int2* __restrict__ csr_ec, int n) {
    int t = threadIdx.x;
    if (t < 16) {
        int2 z0; z0.x = 0; z0.y = 0;
        csr_ec[row_start[n] + t] = z0;
    }
}

// fp32 -> bf16 elementwise (n multiple of 4)
__global__ void f2bf_kernel(const float* __restrict__ in, unsigned short* __restrict__ out, int n4) {
    int i = blockIdx.x * blockDim.x + threadIdx.x;
    if (i < n4) {
        float4 v = ((const float4*)in)[i];
        ushort4 o;
        o.x = f2bf(v.x); o.y = f2bf(v.y); o.z = f2bf(v.z); o.w = f2bf(v.w);
        ((ushort4*)out)[i] = o;
    }
}

// Pack weight W [4ch][K][64] (fp32) into MFMA B-frag layout
__global__ void pack_b_kernel(const float* __restrict__ W, int chanStride, int ksteps,
                              unsigned short* __restrict__ P, int total) {
    int tid = blockIdx.x * blockDim.x + threadIdx.x;
    if (tid >= total) return;
    int j = tid & 7;
    int lane = (tid >> 3) & 63;
    int n = (tid >> 9) & 3;
    int cks = tid >> 11;
    int ks = cks % ksteps;
    int c = cks / ksteps;
    int k = ks * 32 + (lane >> 4) * 8 + j;
    int d = n * 16 + (lane & 15);
    P[tid] = f2bf(W[(size_t)c * chanStride + (size_t)k * 64 + d]);
}

// ---------------- aggregation: z[i] = sum_j coef_j * h[src_j] ----------------
// Full-row, one wave per node (4 nodes/block). lane = (edge group g, sublane sl);
// each lane loads 16 B (8 dims). Adjacent-edge pairing: one int4 load = 2 records;
// per dim-pair: v_perm pack + v_dot2_f32_bf16. 2x unrolled -> 4 gathers in flight.
// Rows padded to x4 edges (coef=0), array end-padded by 16 records.

template<int RS>   // 128 (x / layer0) or 256 (h)
__global__ __launch_bounds__(256) void agg_kernel(
    const unsigned short* __restrict__ h,   // bf16 [N, RS]
    const int* __restrict__ row_start,
    const int2* __restrict__ csr_ec,
    unsigned short* __restrict__ z)         // bf16 [N, RS]
{
    constexpr int LPR = RS / 8;     // lanes per row: 16 or 32
    constexpr int G   = 64 / LPR;   // edge-pair groups: 4 or 2
    int w = threadIdx.x >> 6;
    int lane = threadIdx.x & 63;
    int i = blockIdx.x * 4 + w;
    int g = lane / LPR;
    int sl = lane % LPR;
    int s = row_start[i], e = row_start[i + 1];
    float acc[8] = {};
    const unsigned short* hb = h + sl * 8;

    for (int j0 = s; j0 < e; j0 += 4 * G) {
        int jja = j0 + 2 * g;
        int jjb = j0 + 2 * G + 2 * g;
        int4 ra = *(const int4*)(csr_ec + jja);
        int4 rb = *(const int4*)(csr_ec + jjb);
        unsigned ca = __builtin_amdgcn_perm((unsigned)ra.y, (unsigned)ra.w, 0x01000504u);
        unsigned cb = __builtin_amdgcn_perm((unsigned)rb.y, (unsigned)rb.w, 0x01000504u);
        if constexpr (G > 2) {
            if (jja >= e) ca = 0;   // only reachable when stride exceeds pad granule
        }
        if (jjb >= e) cb = 0;       // second unroll half may cross row end
        uint4 u0a = *(const uint4*)(hb + (size_t)ra.x * RS);
        uint4 u1a = *(const uint4*)(hb + (size_t)ra.z * RS);
        uint4 u0b = *(const uint4*)(hb + (size_t)rb.x * RS);
        uint4 u1b = *(const uint4*)(hb + (size_t)rb.z * RS);
        const unsigned* p0a = (const unsigned*)&u0a;
        const unsigned* p1a = (const unsigned*)&u1a;
        const unsigned* p0b = (const unsigned*)&u0b;
        const unsigned* p1b = (const unsigned*)&u1b;
        #pragma unroll
        for (int q = 0; q < 4; ++q) {
            unsigned loa = __builtin_amdgcn_perm(p0a[q], p1a[q], 0x01000504u);
            unsigned hia = __builtin_amdgcn_perm(p0a[q], p1a[q], 0x03020706u);
            acc[2*q]   = dot2bf(loa, ca, acc[2*q]);
            acc[2*q+1] = dot2bf(hia, ca, acc[2*q+1]);
            unsigned lob = __builtin_amdgcn_perm(p0b[q], p1b[q], 0x01000504u);
            unsigned hib = __builtin_amdgcn_perm(p0b[q], p1b[q], 0x03020706u);
            acc[2*q]   = dot2bf(lob, cb, acc[2*q]);
            acc[2*q+1] = dot2bf(hib, cb, acc[2*q+1]);
        }
    }
    // butterfly-combine across edge groups
    #pragma unroll
    for (int off = LPR; off < 64; off <<= 1)
        #pragma unroll
        for (int q = 0; q < 8; ++q)
            acc[q] += __shfl_xor(acc[q], off, 64);
    if (g == 0) {
        us8 o;
        #pragma unroll
        for (int q = 0; q < 8; ++q) o[q] = f2bf(acc[q]);
        *(us8*)(z + (size_t)i * RS + sl * 8) = o;
    }
}

// ---------------- MFMA GEMM + fused epilogue ----------------
// h' = relu(z@W + b) + (z@W + b); EPI=0: write bf16 h'; EPI=1: LayerNorm -> fp32 out

template<int EPI>
__global__ __launch_bounds__(256) void mfma_gemm_kernel(
    const unsigned short* __restrict__ A, int lda, int aChanOff,
    const unsigned short* __restrict__ Bpack, int ksteps,
    const float* __restrict__ bias, int biasChanStride,
    unsigned short* __restrict__ Cbf,
    float* __restrict__ outF, const float* __restrict__ gamma, const float* __restrict__ beta,
    int M)
{
    int c = blockIdx.y;
    int m0 = blockIdx.x * 64;
    int w = threadIdx.x >> 6, lane = threadIdx.x & 63;
    int arow = m0 + w * 16 + (lane & 15);
    int arow_c = (arow < M) ? arow : (M - 1);
    const unsigned short* Ap = A + (size_t)arow_c * lda + aChanOff * c + (lane >> 4) * 8;
    const unsigned short* Bp = Bpack + ((size_t)c * ksteps * 4) * 512 + (size_t)lane * 8;
    f32x4 acc[4] = {};
    for (int ks = 0; ks < ksteps; ++ks) {
        bf16x8 af = *(const bf16x8*)(Ap + ks * 32);
        const unsigned short* b = Bp + (size_t)ks * 2048;
        #pragma unroll
        for (int n = 0; n < 4; ++n) {
            bf16x8 bfr = *(const bf16x8*)(b + n * 512);
            acc[n] = __builtin_amdgcn_mfma_f32_16x16x32_bf16(af, bfr, acc[n], 0, 0, 0);
        }
    }
    int col = lane & 15;
    int rbase = m0 + w * 16 + (lane >> 4) * 4;
    float hv[4][4];
    #pragma unroll
    for (int n = 0; n < 4; ++n) {
        float bv = bias[c * biasChanStride + n * 16 + col];
        #pragma unroll
        for (int r = 0; r < 4; ++r) {
            float a = acc[n][r] + bv;
            hv[n][r] = (a > 0.f) ? a + a : a;   // relu(a) + a
        }
    }
    if (EPI == 0) {
        #pragma unroll
        for (int n = 0; n < 4; ++n) {
            #pragma unroll
            for (int r = 0; r < 4; ++r) {
                int rr = rbase + r;
                if (rr < M) Cbf[(size_t)rr * D_ALL + c * 64 + n * 16 + col] = f2bf(hv[n][r]);
            }
        }
    } else {
        float sum[4], sq[4];
        #pragma unroll
        for (int r = 0; r < 4; ++r) {
            sum[r] = hv[0][r] + hv[1][r] + hv[2][r] + hv[3][r];
            sq[r] = hv[0][r]*hv[0][r] + hv[1][r]*hv[1][r] + hv[2][r]*hv[2][r] + hv[3][r]*hv[3][r];
        }
        #pragma unroll
        for (int off = 1; off < 16; off <<= 1) {
            #pragma unroll
            for (int r = 0; r < 4; ++r) {
                sum[r] += __shfl_xor(sum[r], off, 64);
                sq[r]  += __shfl_xor(sq[r], off, 64);
            }
        }
        float mu[4], rinv[4];
        #pragma unroll
        for (int r = 0; r < 4; ++r) {
            mu[r] = sum[r] * (1.f / 64.f);
            float var = sq[r] * (1.f / 64.f) - mu[r] * mu[r];
            rinv[r] = rsqrtf(var + 1e-6f);
        }
        #pragma unroll
        for (int n = 0; n < 4; ++n) {
            float gv = gamma[n * 16 + col];
            float bv2 = beta[n * 16 + col];
            #pragma unroll
            for (int r = 0; r < 4; ++r) {
                int rr = rbase + r;
                if (rr < M)
                    outF[(size_t)c * N_NODES * D_H + (size_t)rr * D_H + n * 16 + col] =
                        (hv[n][r] - mu[r]) * rinv[r] * gv + bv2;
            }
        }
    }
}

// ---------------- launch ----------------

extern "C" void kernel_launch(void* const* d_in, const int* in_sizes, int n_in,
                              void* d_out, int out_size, void* d_ws, size_t ws_size,
                              hipStream_t stream) {
    const float* x     = (const float*)d_in[0];
    const int*   edge  = (const int*)d_in[1];
    const float* W0    = (const float*)d_in[3];
    const float* b0    = (const float*)d_in[4];
    const float* Wl    = (const float*)d_in[5];
    const float* bl    = (const float*)d_in[6];
    const float* gamma = (const float*)d_in[7];
    const float* beta  = (const float*)d_in[8];
    float* out = (float*)d_out;

    const int* e_src = edge;            // edge[0]
    const int* e_dst = edge + N_EDGES;  // edge[1]

    char* ws = (char*)d_ws;
    size_t off = 0;
    auto alloc = [&](size_t bytes) -> void* {
        void* p = ws + off;
        off = (off + bytes + 255) & ~(size_t)255;
        return p;
    };
    const int NE_MAX = N_EDGES + 4 * N_NODES + 16;   // padded rows + end pad
    const int NB_SCAN = (N_NODES + 1023) / 1024;     // 49
    int*   deg_cnt   = (int*)  alloc(sizeof(int)   * N_NODES);
    int*   cursor    = (int*)  alloc(sizeof(int)   * N_NODES);
    int*   padlen    = (int*)  alloc(sizeof(int)   * N_NODES);
    int*   row_start = (int*)  alloc(sizeof(int)   * (N_NODES + 1));
    int*   bsum      = (int*)  alloc(sizeof(int)   * 64);
    float* dinv      = (float*)alloc(sizeof(float) * N_NODES);
    int2*  csr_ec    = (int2*) alloc(sizeof(int2)  * NE_MAX);
    unsigned short* x_bf  = (unsigned short*)alloc(sizeof(unsigned short) * (size_t)N_NODES * D_IN);
    unsigned short* W0p   = (unsigned short*)alloc(sizeof(unsigned short) * SZ_C * 4 * 4 * 512);
    unsigned short* Wl0p  = (unsigned short*)alloc(sizeof(unsigned short) * SZ_C * 2 * 4 * 512);
    unsigned short* Wl1p  = (unsigned short*)alloc(sizeof(unsigned short) * SZ_C * 2 * 4 * 512);
    unsigned short* zbuf  = (unsigned short*)alloc(sizeof(unsigned short) * (size_t)N_NODES * D_ALL);
    unsigned short* h_bf  = (unsigned short*)alloc(sizeof(unsigned short) * (size_t)N_NODES * D_ALL);

    const int nb_n = (N_NODES + 255) / 256;
    const int nb_e = (N_EDGES + 255) / 256;

    init_deg_kernel<<<nb_n, 256, 0, stream>>>(deg_cnt, cursor, N_NODES);
    hist_kernel<<<nb_e, 256, 0, stream>>>(e_dst, deg_cnt, N_EDGES);
    dinv_kernel<<<nb_n, 256, 0, stream>>>(deg_cnt, dinv, padlen, N_NODES);
    scan_block_kernel<<<NB_SCAN, 1024, 0, stream>>>(padlen, row_start, bsum, N_NODES);
    scan_tot_kernel<<<1, 64, 0, stream>>>(bsum, NB_SCAN);
    scan_add_kernel<<<NB_SCAN, 1024, 0, stream>>>(bsum, row_start, N_NODES);
    csr_build_kernel<<<nb_e, 256, 0, stream>>>(e_src, e_dst, row_start, cursor, dinv,
                                               csr_ec, N_EDGES);
    self_pad_kernel<<<nb_n, 256, 0, stream>>>(row_start, deg_cnt, dinv, csr_ec, N_NODES);
    end_pad_kernel<<<1, 64, 0, stream>>>(row_start, csr_ec, N_NODES);
    // weight packing + x conversion
    pack_b_kernel<<<(SZ_C * 4 * 4 * 512 + 255) / 256, 256, 0, stream>>>(
        W0, D_IN * D_H, 4, W0p, SZ_C * 4 * 4 * 512);
    pack_b_kernel<<<(SZ_C * 2 * 4 * 512 + 255) / 256, 256, 0, stream>>>(
        Wl, 2 * D_H * D_H, 2, Wl0p, SZ_C * 2 * 4 * 512);
    pack_b_kernel<<<(SZ_C * 2 * 4 * 512 + 255) / 256, 256, 0, stream>>>(
        Wl + D_H * D_H, 2 * D_H * D_H, 2, Wl1p, SZ_C * 2 * 4 * 512);
    f2bf_kernel<<<((N_NODES * D_IN / 4) + 255) / 256, 256, 0, stream>>>(
        x, x_bf, N_NODES * D_IN / 4);

    dim3 ggrid((N_NODES + 63) / 64, SZ_C);
    const int agg_grid = N_NODES / 4;  // 12500

    // layer 0: z = agg(x_bf) [N,128]; h = relures(z@W0 + b0) [N,256]
    agg_kernel<D_IN><<<agg_grid, 256, 0, stream>>>(x_bf, row_start, csr_ec, zbuf);
    mfma_gemm_kernel<0><<<ggrid, 256, 0, stream>>>(zbuf, D_IN, 0, W0p, 4,
                                                   b0, 64, h_bf, nullptr, nullptr, nullptr, N_NODES);
    // layer 1: z = agg(h) [N,256]; h = relures(z@Wl0 + bl0)
    agg_kernel<D_ALL><<<agg_grid, 256, 0, stream>>>(h_bf, row_start, csr_ec, zbuf);
    mfma_gemm_kernel<0><<<ggrid, 256, 0, stream>>>(zbuf, D_ALL, 64, Wl0p, 2,
                                                   bl, 2 * 64, h_bf, nullptr, nullptr, nullptr, N_NODES);
    // layer 2: z = agg(h); out = LN(relures(z@Wl1 + bl1)) -> d_out fp32
    agg_kernel<D_ALL><<<agg_grid, 256, 0, stream>>>(h_bf, row_start, csr_ec, zbuf);
    mfma_gemm_kernel<1><<<ggrid, 256, 0, stream>>>(zbuf, D_ALL, 64, Wl1p, 2,
                                                   bl + 64, 2 * 64, nullptr, out, gamma, beta, N_NODES);
}

// Round 7
// 305.630 us; speedup vs baseline: 1.1784x; 1.0269x over previous
//
#include <hip/hip_runtime.h>
#include <hip/hip_bf16.h>

#define N_NODES 50000
#define N_EDGES 800000
#define D_IN    128
#define D_H     64
#define SZ_C    4
#define D_ALL   (SZ_C * D_H)   // 256

typedef __bf16 bf16x8 __attribute__((ext_vector_type(8)));
typedef __bf16 bf16x2 __attribute__((ext_vector_type(2)));
typedef float  f32x4  __attribute__((ext_vector_type(4)));
typedef unsigned short us8 __attribute__((ext_vector_type(8)));

#if defined(__has_builtin)
#if __has_builtin(__builtin_amdgcn_fdot2_f32_bf16)
#define HAVE_DOT2 1
#else
#define HAVE_DOT2 0
#endif
#else
#define HAVE_DOT2 0
#endif

__device__ __forceinline__ float bf2f(unsigned short u) {
    return __uint_as_float(((unsigned)u) << 16);
}
__device__ __forceinline__ unsigned short f2bf(float f) {
    unsigned u = __float_as_uint(f);
    unsigned r = (u + 0x7fffu + ((u >> 16) & 1u)) >> 16;   // round-to-nearest-even
    return (unsigned short)r;
}

// acc += a.lo*c.lo + a.hi*c.hi, bf16 pairs in u32, f32 accumulate
__device__ __forceinline__ float dot2bf(unsigned ab, unsigned cc, float acc) {
#if HAVE_DOT2
    return __builtin_amdgcn_fdot2_f32_bf16(__builtin_bit_cast(bf16x2, ab),
                                           __builtin_bit_cast(bf16x2, cc), acc, false);
#else
    float a0 = __uint_as_float(ab << 16);
    float a1 = __uint_as_float(ab & 0xffff0000u);
    float c0 = __uint_as_float(cc << 16);
    float c1 = __uint_as_float(cc & 0xffff0000u);
    return acc + a0 * c0 + a1 * c1;
#endif
}

// ---------------- setup kernels ----------------

// deg starts at 1: self-loop slot; matches reference deg = in_deg + 1.
__global__ void init_deg_kernel(int* __restrict__ deg_cnt, int* __restrict__ cursor, int n) {
    int i = blockIdx.x * blockDim.x + threadIdx.x;
    if (i < n) { deg_cnt[i] = 1; cursor[i] = 0; }
}

__global__ void hist_kernel(const int* __restrict__ dst, int* __restrict__ deg_cnt, int e) {
    int i = blockIdx.x * blockDim.x + threadIdx.x;
    if (i < e) atomicAdd(&deg_cnt[dst[i]], 1);
}

// dinv + padded row length (multiple of 16 -> guard-free 16-edge iterations)
__global__ void dinv_kernel(const int* __restrict__ deg_cnt, float* __restrict__ dinv,
                            int* __restrict__ padlen, int n) {
    int i = blockIdx.x * blockDim.x + threadIdx.x;
    if (i < n) {
        dinv[i] = rsqrtf((float)deg_cnt[i]);
        padlen[i] = (deg_cnt[i] + 15) & ~15;
    }
}

// ---- 3-phase scan over padlen ----

__global__ __launch_bounds__(1024) void scan_block_kernel(
    const int* __restrict__ cnt, int* __restrict__ row_start, int* __restrict__ bsum, int n) {
    __shared__ int wsum[16];
    int t = threadIdx.x;
    int lane = t & 63, wv = t >> 6;
    int base = blockIdx.x * 1024;
    int v = (base + t < n) ? cnt[base + t] : 0;
    int x = v;
    #pragma unroll
    for (int off = 1; off < 64; off <<= 1) {
        int y = __shfl_up(x, off, 64);
        if (lane >= off) x += y;
    }
    if (lane == 63) wsum[wv] = x;
    __syncthreads();
    if (wv == 0 && lane < 16) {
        int ws = wsum[lane];
        #pragma unroll
        for (int off = 1; off < 16; off <<= 1) {
            int y = __shfl_up(ws, off, 64);
            if (lane >= off) ws += y;
        }
        wsum[lane] = ws;
    }
    __syncthreads();
    int wbase = (wv == 0) ? 0 : wsum[wv - 1];
    int incl = x + wbase;
    if (base + t < n) row_start[base + t + 1] = incl;
    if (t == 1023) bsum[blockIdx.x] = incl;
}

__global__ void scan_tot_kernel(int* __restrict__ bsum, int nb) {
    int lane = threadIdx.x;   // one wave
    int v = (lane < nb) ? bsum[lane] : 0;
    int x = v;
    #pragma unroll
    for (int off = 1; off < 64; off <<= 1) {
        int y = __shfl_up(x, off, 64);
        if (lane >= off) x += y;
    }
    if (lane < nb) bsum[lane] = x - v;   // exclusive
}

__global__ __launch_bounds__(1024) void scan_add_kernel(
    const int* __restrict__ bsum, int* __restrict__ row_start, int n) {
    int b = blockIdx.x, t = threadIdx.x;
    int i = b * 1024 + t;
    if (b == 0 && t == 0) row_start[0] = 0;
    if (i < n) row_start[i + 1] += bsum[b];
}

// scatter real edges; record = (src, bf16(coef) in low16)
__global__ void csr_build_kernel(const int* __restrict__ src, const int* __restrict__ dst,
                                 const int* __restrict__ row_start, int* __restrict__ cursor,
                                 const float* __restrict__ dinv,
                                 int2* __restrict__ csr_ec, int e) {
    int i = blockIdx.x * blockDim.x + threadIdx.x;
    if (i < e) {
        int d = dst[i];
        int s = src[i];
        int pos = row_start[d] + atomicAdd(&cursor[d], 1);
        int2 rec;
        rec.x = s;
        rec.y = (int)(unsigned)f2bf(dinv[s] * dinv[d]);
        csr_ec[pos] = rec;
    }
}

// self edge + zero-coef padding up to padded row length (pads gather row 0 -> L1-hot)
__global__ void self_pad_kernel(const int* __restrict__ row_start, const int* __restrict__ deg_cnt,
                                const float* __restrict__ dinv, int2* __restrict__ csr_ec, int n) {
    int i = blockIdx.x * blockDim.x + threadIdx.x;
    if (i < n) {
        int s = row_start[i], e = row_start[i + 1];
        int selfslot = s + deg_cnt[i] - 1;
        float dv = dinv[i];
        int2 rec;
        rec.x = i;
        rec.y = (int)(unsigned)f2bf(dv * dv);
        csr_ec[selfslot] = rec;
        rec.x = 0;
        rec.y = 0;
        for (int k = selfslot + 1; k < e; ++k) csr_ec[k] = rec;
    }
}

// 32 (0,0) records past the end: safe target for pipelined read-ahead
__global__ void end_pad_kernel(const int* __restrict__ row_start, int2* __restrict__ csr_ec, int n) {
    int t = threadIdx.x;
    if (t < 32) {
        int2 z0; z0.x = 0; z0.y = 0;
        csr_ec[row_start[n] + t] = z0;
    }
}

// fp32 -> bf16 elementwise (n multiple of 4)
__global__ void f2bf_kernel(const float* __restrict__ in, unsigned short* __restrict__ out, int n4) {
    int i = blockIdx.x * blockDim.x + threadIdx.x;
    if (i < n4) {
        float4 v = ((const float4*)in)[i];
        ushort4 o;
        o.x = f2bf(v.x); o.y = f2bf(v.y); o.z = f2bf(v.z); o.w = f2bf(v.w);
        ((ushort4*)out)[i] = o;
    }
}

// Pack weight W [4ch][K][64] (fp32) into MFMA B-frag layout
__global__ void pack_b_kernel(const float* __restrict__ W, int chanStride, int ksteps,
                              unsigned short* __restrict__ P, int total) {
    int tid = blockIdx.x * blockDim.x + threadIdx.x;
    if (tid >= total) return;
    int j = tid & 7;
    int lane = (tid >> 3) & 63;
    int n = (tid >> 9) & 3;
    int cks = tid >> 11;
    int ks = cks % ksteps;
    int c = cks / ksteps;
    int k = ks * 32 + (lane >> 4) * 8 + j;
    int d = n * 16 + (lane & 15);
    P[tid] = f2bf(W[(size_t)c * chanStride + (size_t)k * 64 + d]);
}

// ---------------- aggregation: z[i] = sum_j coef_j * h[src_j] ----------------
// One wave per node (4 nodes/block). Rows padded to x16 edges: guard-free.
// 16 edges/iter; RS=256 -> 8 row-gathers in flight per lane; RS=128 -> 4.
// Record loads for iter t+1 issued under iter t's VALU (end-pad makes it safe).

template<int RS>   // 128 (x / layer0) or 256 (h)
__global__ __launch_bounds__(256) void agg_kernel(
    const unsigned short* __restrict__ h,   // bf16 [N, RS]
    const int* __restrict__ row_start,
    const int2* __restrict__ csr_ec,
    unsigned short* __restrict__ z)         // bf16 [N, RS]
{
    constexpr int LPR = RS / 8;          // lanes per row: 16 or 32
    constexpr int G = 64 / LPR;          // edge-pair groups: 4 or 2
    constexpr int SLOTS = 16 / (2 * G);  // record-pair slots per iter: 2 or 4
    int w = threadIdx.x >> 6;
    int lane = threadIdx.x & 63;
    int i = blockIdx.x * 4 + w;
    int g = lane / LPR;
    int sl = lane % LPR;
    int s = row_start[i], e = row_start[i + 1];
    float acc[8] = {};
    const unsigned short* hb = h + sl * 8;

    int4 r[SLOTS];
    #pragma unroll
    for (int u = 0; u < SLOTS; ++u)
        r[u] = *(const int4*)(csr_ec + s + u * (2 * G) + 2 * g);

    for (int j0 = s; j0 < e; j0 += 16) {
        // issue gathers for current records
        uint4 row0[SLOTS], row1[SLOTS];
        #pragma unroll
        for (int u = 0; u < SLOTS; ++u) {
            row0[u] = *(const uint4*)(hb + (size_t)r[u].x * RS);
            row1[u] = *(const uint4*)(hb + (size_t)r[u].z * RS);
        }
        // issue next iteration's record loads (end-pad keeps this in bounds)
        int4 rn[SLOTS];
        #pragma unroll
        for (int u = 0; u < SLOTS; ++u)
            rn[u] = *(const int4*)(csr_ec + (j0 + 16) + u * (2 * G) + 2 * g);
        // compute
        #pragma unroll
        for (int u = 0; u < SLOTS; ++u) {
            unsigned cc = __builtin_amdgcn_perm((unsigned)r[u].y, (unsigned)r[u].w, 0x01000504u);
            const unsigned* p0 = (const unsigned*)&row0[u];
            const unsigned* p1 = (const unsigned*)&row1[u];
            #pragma unroll
            for (int q = 0; q < 4; ++q) {
                unsigned lo = __builtin_amdgcn_perm(p0[q], p1[q], 0x01000504u);
                unsigned hi = __builtin_amdgcn_perm(p0[q], p1[q], 0x03020706u);
                acc[2*q]   = dot2bf(lo, cc, acc[2*q]);
                acc[2*q+1] = dot2bf(hi, cc, acc[2*q+1]);
            }
        }
        #pragma unroll
        for (int u = 0; u < SLOTS; ++u) r[u] = rn[u];
    }
    // butterfly-combine across edge groups
    #pragma unroll
    for (int off = LPR; off < 64; off <<= 1)
        #pragma unroll
        for (int q = 0; q < 8; ++q)
            acc[q] += __shfl_xor(acc[q], off, 64);
    if (g == 0) {
        us8 o;
        #pragma unroll
        for (int q = 0; q < 8; ++q) o[q] = f2bf(acc[q]);
        *(us8*)(z + (size_t)i * RS + sl * 8) = o;
    }
}

// ---------------- MFMA GEMM + fused epilogue ----------------
// h' = relu(z@W + b) + (z@W + b); EPI=0: write bf16 h'; EPI=1: LayerNorm -> fp32 out

template<int EPI>
__global__ __launch_bounds__(256) void mfma_gemm_kernel(
    const unsigned short* __restrict__ A, int lda, int aChanOff,
    const unsigned short* __restrict__ Bpack, int ksteps,
    const float* __restrict__ bias, int biasChanStride,
    unsigned short* __restrict__ Cbf,
    float* __restrict__ outF, const float* __restrict__ gamma, const float* __restrict__ beta,
    int M)
{
    int c = blockIdx.y;
    int m0 = blockIdx.x * 64;
    int w = threadIdx.x >> 6, lane = threadIdx.x & 63;
    int arow = m0 + w * 16 + (lane & 15);
    int arow_c = (arow < M) ? arow : (M - 1);
    const unsigned short* Ap = A + (size_t)arow_c * lda + aChanOff * c + (lane >> 4) * 8;
    const unsigned short* Bp = Bpack + ((size_t)c * ksteps * 4) * 512 + (size_t)lane * 8;
    f32x4 acc[4] = {};
    for (int ks = 0; ks < ksteps; ++ks) {
        bf16x8 af = *(const bf16x8*)(Ap + ks * 32);
        const unsigned short* b = Bp + (size_t)ks * 2048;
        #pragma unroll
        for (int n = 0; n < 4; ++n) {
            bf16x8 bfr = *(const bf16x8*)(b + n * 512);
            acc[n] = __builtin_amdgcn_mfma_f32_16x16x32_bf16(af, bfr, acc[n], 0, 0, 0);
        }
    }
    int col = lane & 15;
    int rbase = m0 + w * 16 + (lane >> 4) * 4;
    float hv[4][4];
    #pragma unroll
    for (int n = 0; n < 4; ++n) {
        float bv = bias[c * biasChanStride + n * 16 + col];
        #pragma unroll
        for (int r = 0; r < 4; ++r) {
            float a = acc[n][r] + bv;
            hv[n][r] = (a > 0.f) ? a + a : a;   // relu(a) + a
        }
    }
    if (EPI == 0) {
        #pragma unroll
        for (int n = 0; n < 4; ++n) {
            #pragma unroll
            for (int r = 0; r < 4; ++r) {
                int rr = rbase + r;
                if (rr < M) Cbf[(size_t)rr * D_ALL + c * 64 + n * 16 + col] = f2bf(hv[n][r]);
            }
        }
    } else {
        float sum[4], sq[4];
        #pragma unroll
        for (int r = 0; r < 4; ++r) {
            sum[r] = hv[0][r] + hv[1][r] + hv[2][r] + hv[3][r];
            sq[r] = hv[0][r]*hv[0][r] + hv[1][r]*hv[1][r] + hv[2][r]*hv[2][r] + hv[3][r]*hv[3][r];
        }
        #pragma unroll
        for (int off = 1; off < 16; off <<= 1) {
            #pragma unroll
            for (int r = 0; r < 4; ++r) {
                sum[r] += __shfl_xor(sum[r], off, 64);
                sq[r]  += __shfl_xor(sq[r], off, 64);
            }
        }
        float mu[4], rinv[4];
        #pragma unroll
        for (int r = 0; r < 4; ++r) {
            mu[r] = sum[r] * (1.f / 64.f);
            float var = sq[r] * (1.f / 64.f) - mu[r] * mu[r];
            rinv[r] = rsqrtf(var + 1e-6f);
        }
        #pragma unroll
        for (int n = 0; n < 4; ++n) {
            float gv = gamma[n * 16 + col];
            float bv2 = beta[n * 16 + col];
            #pragma unroll
            for (int r = 0; r < 4; ++r) {
                int rr = rbase + r;
                if (rr < M)
                    outF[(size_t)c * N_NODES * D_H + (size_t)rr * D_H + n * 16 + col] =
                        (hv[n][r] - mu[r]) * rinv[r] * gv + bv2;
            }
        }
    }
}

// ---------------- launch ----------------

extern "C" void kernel_launch(void* const* d_in, const int* in_sizes, int n_in,
                              void* d_out, int out_size, void* d_ws, size_t ws_size,
                              hipStream_t stream) {
    const float* x     = (const float*)d_in[0];
    const int*   edge  = (const int*)d_in[1];
    const float* W0    = (const float*)d_in[3];
    const float* b0    = (const float*)d_in[4];
    const float* Wl    = (const float*)d_in[5];
    const float* bl    = (const float*)d_in[6];
    const float* gamma = (const float*)d_in[7];
    const float* beta  = (const float*)d_in[8];
    float* out = (float*)d_out;

    const int* e_src = edge;            // edge[0]
    const int* e_dst = edge + N_EDGES;  // edge[1]

    char* ws = (char*)d_ws;
    size_t off = 0;
    auto alloc = [&](size_t bytes) -> void* {
        void* p = ws + off;
        off = (off + bytes + 255) & ~(size_t)255;
        return p;
    };
    const int NE_MAX = N_EDGES + 16 * N_NODES + 32;   // x16-padded rows + end pad
    const int NB_SCAN = (N_NODES + 1023) / 1024;      // 49
    int*   deg_cnt   = (int*)  alloc(sizeof(int)   * N_NODES);
    int*   cursor    = (int*)  alloc(sizeof(int)   * N_NODES);
    int*   padlen    = (int*)  alloc(sizeof(int)   * N_NODES);
    int*   row_start = (int*)  alloc(sizeof(int)   * (N_NODES + 1));
    int*   bsum      = (int*)  alloc(sizeof(int)   * 64);
    float* dinv      = (float*)alloc(sizeof(float) * N_NODES);
    int2*  csr_ec    = (int2*) alloc(sizeof(int2)  * NE_MAX);
    unsigned short* x_bf  = (unsigned short*)alloc(sizeof(unsigned short) * (size_t)N_NODES * D_IN);
    unsigned short* W0p   = (unsigned short*)alloc(sizeof(unsigned short) * SZ_C * 4 * 4 * 512);
    unsigned short* Wl0p  = (unsigned short*)alloc(sizeof(unsigned short) * SZ_C * 2 * 4 * 512);
    unsigned short* Wl1p  = (unsigned short*)alloc(sizeof(unsigned short) * SZ_C * 2 * 4 * 512);
    unsigned short* zbuf  = (unsigned short*)alloc(sizeof(unsigned short) * (size_t)N_NODES * D_ALL);
    unsigned short* h_bf  = (unsigned short*)alloc(sizeof(unsigned short) * (size_t)N_NODES * D_ALL);

    const int nb_n = (N_NODES + 255) / 256;
    const int nb_e = (N_EDGES + 255) / 256;

    init_deg_kernel<<<nb_n, 256, 0, stream>>>(deg_cnt, cursor, N_NODES);
    hist_kernel<<<nb_e, 256, 0, stream>>>(e_dst, deg_cnt, N_EDGES);
    dinv_kernel<<<nb_n, 256, 0, stream>>>(deg_cnt, dinv, padlen, N_NODES);
    scan_block_kernel<<<NB_SCAN, 1024, 0, stream>>>(padlen, row_start, bsum, N_NODES);
    scan_tot_kernel<<<1, 64, 0, stream>>>(bsum, NB_SCAN);
    scan_add_kernel<<<NB_SCAN, 1024, 0, stream>>>(bsum, row_start, N_NODES);
    csr_build_kernel<<<nb_e, 256, 0, stream>>>(e_src, e_dst, row_start, cursor, dinv,
                                               csr_ec, N_EDGES);
    self_pad_kernel<<<nb_n, 256, 0, stream>>>(row_start, deg_cnt, dinv, csr_ec, N_NODES);
    end_pad_kernel<<<1, 64, 0, stream>>>(row_start, csr_ec, N_NODES);
    // weight packing + x conversion
    pack_b_kernel<<<(SZ_C * 4 * 4 * 512 + 255) / 256, 256, 0, stream>>>(
        W0, D_IN * D_H, 4, W0p, SZ_C * 4 * 4 * 512);
    pack_b_kernel<<<(SZ_C * 2 * 4 * 512 + 255) / 256, 256, 0, stream>>>(
        Wl, 2 * D_H * D_H, 2, Wl0p, SZ_C * 2 * 4 * 512);
    pack_b_kernel<<<(SZ_C * 2 * 4 * 512 + 255) / 256, 256, 0, stream>>>(
        Wl + D_H * D_H, 2 * D_H * D_H, 2, Wl1p, SZ_C * 2 * 4 * 512);
    f2bf_kernel<<<((N_NODES * D_IN / 4) + 255) / 256, 256, 0, stream>>>(
        x, x_bf, N_NODES * D_IN / 4);

    dim3 ggrid((N_NODES + 63) / 64, SZ_C);
    const int agg_grid = N_NODES / 4;  // 12500

    // layer 0: z = agg(x_bf) [N,128]; h = relures(z@W0 + b0) [N,256]
    agg_kernel<D_IN><<<agg_grid, 256, 0, stream>>>(x_bf, row_start, csr_ec, zbuf);
    mfma_gemm_kernel<0><<<ggrid, 256, 0, stream>>>(zbuf, D_IN, 0, W0p, 4,
                                                   b0, 64, h_bf, nullptr, nullptr, nullptr, N_NODES);
    // layer 1: z = agg(h) [N,256]; h = relures(z@Wl0 + bl0)
    agg_kernel<D_ALL><<<agg_grid, 256, 0, stream>>>(h_bf, row_start, csr_ec, zbuf);
    mfma_gemm_kernel<0><<<ggrid, 256, 0, stream>>>(zbuf, D_ALL, 64, Wl0p, 2,
                                                   bl, 2 * 64, h_bf, nullptr, nullptr, nullptr, N_NODES);
    // layer 2: z = agg(h); out = LN(relures(z@Wl1 + bl1)) -> d_out fp32
    agg_kernel<D_ALL><<<agg_grid, 256, 0, stream>>>(h_bf, row_start, csr_ec, zbuf);
    mfma_gemm_kernel<1><<<ggrid, 256, 0, stream>>>(zbuf, D_ALL, 64, Wl1p, 2,
                                                   bl + 64, 2 * 64, nullptr, out, gamma, beta, N_NODES);
}

// Round 8
// 291.419 us; speedup vs baseline: 1.2359x; 1.0488x over previous
//
#include <hip/hip_runtime.h>
#include <hip/hip_bf16.h>

#define N_NODES 50000
#define N_EDGES 800000
#define D_IN    128
#define D_H     64
#define SZ_C    4
#define D_ALL   (SZ_C * D_H)   // 256

typedef __bf16 bf16x8 __attribute__((ext_vector_type(8)));
typedef __bf16 bf16x2 __attribute__((ext_vector_type(2)));
typedef float  f32x4  __attribute__((ext_vector_type(4)));
typedef unsigned short us8 __attribute__((ext_vector_type(8)));

#if defined(__has_builtin)
#if __has_builtin(__builtin_amdgcn_fdot2_f32_bf16)
#define HAVE_DOT2 1
#else
#define HAVE_DOT2 0
#endif
#else
#define HAVE_DOT2 0
#endif

__device__ __forceinline__ float bf2f(unsigned short u) {
    return __uint_as_float(((unsigned)u) << 16);
}
__device__ __forceinline__ unsigned short f2bf(float f) {
    unsigned u = __float_as_uint(f);
    unsigned r = (u + 0x7fffu + ((u >> 16) & 1u)) >> 16;   // round-to-nearest-even
    return (unsigned short)r;
}

// acc += a.lo*c.lo + a.hi*c.hi, bf16 pairs in u32, f32 accumulate
__device__ __forceinline__ float dot2bf(unsigned ab, unsigned cc, float acc) {
#if HAVE_DOT2
    return __builtin_amdgcn_fdot2_f32_bf16(__builtin_bit_cast(bf16x2, ab),
                                           __builtin_bit_cast(bf16x2, cc), acc, false);
#else
    float a0 = __uint_as_float(ab << 16);
    float a1 = __uint_as_float(ab & 0xffff0000u);
    float c0 = __uint_as_float(cc << 16);
    float c1 = __uint_as_float(cc & 0xffff0000u);
    return acc + a0 * c0 + a1 * c1;
#endif
}

// ---------------- setup kernels (fused) ----------------

// x->bf16 conversion + deg/cursor init in one launch.
// deg starts at 1: self-loop slot; matches reference deg = in_deg + 1.
__global__ void init_f2bf_kernel(const float* __restrict__ x, unsigned short* __restrict__ x_bf,
                                 int n4, int* __restrict__ deg_cnt, int* __restrict__ cursor, int n) {
    int i = blockIdx.x * blockDim.x + threadIdx.x;
    if (i < n) { deg_cnt[i] = 1; cursor[i] = 0; }
    if (i < n4) {
        float4 v = ((const float4*)x)[i];
        ushort4 o;
        o.x = f2bf(v.x); o.y = f2bf(v.y); o.z = f2bf(v.z); o.w = f2bf(v.w);
        ((ushort4*)x_bf)[i] = o;
    }
}

__global__ void hist_kernel(const int* __restrict__ dst, int* __restrict__ deg_cnt, int e) {
    int i = blockIdx.x * blockDim.x + threadIdx.x;
    if (i < e) atomicAdd(&deg_cnt[dst[i]], 1);
}

// scan phase 1 over padlen=(deg+7)&~7 computed inline; also emits dinv.
__global__ __launch_bounds__(1024) void scan_block_kernel(
    const int* __restrict__ deg_cnt, float* __restrict__ dinv,
    int* __restrict__ row_start, int* __restrict__ bsum, int n) {
    __shared__ int wsum[16];
    int t = threadIdx.x;
    int lane = t & 63, wv = t >> 6;
    int base = blockIdx.x * 1024;
    int v = 0;
    if (base + t < n) {
        int dg = deg_cnt[base + t];
        dinv[base + t] = rsqrtf((float)dg);
        v = (dg + 7) & ~7;
    }
    int x = v;
    #pragma unroll
    for (int off = 1; off < 64; off <<= 1) {
        int y = __shfl_up(x, off, 64);
        if (lane >= off) x += y;
    }
    if (lane == 63) wsum[wv] = x;
    __syncthreads();
    if (wv == 0 && lane < 16) {
        int ws = wsum[lane];
        #pragma unroll
        for (int off = 1; off < 16; off <<= 1) {
            int y = __shfl_up(ws, off, 64);
            if (lane >= off) ws += y;
        }
        wsum[lane] = ws;
    }
    __syncthreads();
    int wbase = (wv == 0) ? 0 : wsum[wv - 1];
    int incl = x + wbase;
    if (base + t < n) row_start[base + t + 1] = incl;
    if (t == 1023) bsum[blockIdx.x] = incl;
}

__global__ void scan_tot_kernel(int* __restrict__ bsum, int nb) {
    int lane = threadIdx.x;   // one wave
    int v = (lane < nb) ? bsum[lane] : 0;
    int x = v;
    #pragma unroll
    for (int off = 1; off < 64; off <<= 1) {
        int y = __shfl_up(x, off, 64);
        if (lane >= off) x += y;
    }
    if (lane < nb) bsum[lane] = x - v;   // exclusive
}

__global__ __launch_bounds__(1024) void scan_add_kernel(
    const int* __restrict__ bsum, int* __restrict__ row_start, int n) {
    int b = blockIdx.x, t = threadIdx.x;
    int i = b * 1024 + t;
    if (b == 0 && t == 0) row_start[0] = 0;
    if (i < n) row_start[i + 1] += bsum[b];
}

// scatter real edges; record = (src, bf16(coef) in low16)
__global__ void csr_build_kernel(const int* __restrict__ src, const int* __restrict__ dst,
                                 const int* __restrict__ row_start, int* __restrict__ cursor,
                                 const float* __restrict__ dinv,
                                 int2* __restrict__ csr_ec, int e) {
    int i = blockIdx.x * blockDim.x + threadIdx.x;
    if (i < e) {
        int d = dst[i];
        int s = src[i];
        int pos = row_start[d] + atomicAdd(&cursor[d], 1);
        int2 rec;
        rec.x = s;
        rec.y = (int)(unsigned)f2bf(dinv[s] * dinv[d]);
        csr_ec[pos] = rec;
    }
}

// self edge + zero-coef padding (gather row 0 -> L1-hot) + 32 end-pad records
__global__ void self_pad_kernel(const int* __restrict__ row_start, const int* __restrict__ deg_cnt,
                                const float* __restrict__ dinv, int2* __restrict__ csr_ec, int n) {
    int i = blockIdx.x * blockDim.x + threadIdx.x;
    if (i < n) {
        int s = row_start[i], e = row_start[i + 1];
        int selfslot = s + deg_cnt[i] - 1;
        float dv = dinv[i];
        int2 rec;
        rec.x = i;
        rec.y = (int)(unsigned)f2bf(dv * dv);
        csr_ec[selfslot] = rec;
        rec.x = 0;
        rec.y = 0;
        for (int k = selfslot + 1; k < e; ++k) csr_ec[k] = rec;
    }
    if (i < 32) {
        int2 z0; z0.x = 0; z0.y = 0;
        csr_ec[row_start[n] + i] = z0;
    }
}

// Pack all three weight tensors into MFMA B-frag layout; blockIdx.y selects tensor.
// P[((c*ksteps + ks)*4 + nn)*512 + lane*8 + j] = bf16(W[c][ks*32 + (lane>>4)*8 + j][nn*16 + (lane&15)])
__global__ void pack_all_kernel(const float* __restrict__ W0, const float* __restrict__ Wl,
                                unsigned short* __restrict__ W0p,
                                unsigned short* __restrict__ Wl0p,
                                unsigned short* __restrict__ Wl1p) {
    int tid = blockIdx.x * blockDim.x + threadIdx.x;
    int which = blockIdx.y;
    const float* W;
    unsigned short* P;
    int ksteps, total, chanStride;
    if (which == 0)      { W = W0;                P = W0p;  ksteps = 4; total = SZ_C * 4 * 4 * 512; chanStride = D_IN * D_H; }
    else if (which == 1) { W = Wl;                P = Wl0p; ksteps = 2; total = SZ_C * 2 * 4 * 512; chanStride = 2 * D_H * D_H; }
    else                 { W = Wl + D_H * D_H;    P = Wl1p; ksteps = 2; total = SZ_C * 2 * 4 * 512; chanStride = 2 * D_H * D_H; }
    if (tid >= total) return;
    int j = tid & 7;
    int lane = (tid >> 3) & 63;
    int nn = (tid >> 9) & 3;
    int cks = tid >> 11;
    int ks = cks % ksteps;
    int c = cks / ksteps;
    int k = ks * 32 + (lane >> 4) * 8 + j;
    int d = nn * 16 + (lane & 15);
    P[tid] = f2bf(W[(size_t)c * chanStride + (size_t)k * 64 + d]);
}

// ---------------- aggregation: z[i] = sum_j coef_j * h[src_j] ----------------
// One wave per node (2 nodes / 128-thread block). Rows padded to x8.
// Main loop: guard-free 16 edges/iter (RS=256: 8 row-gathers in flight/lane);
// record loads for iter t+1 issued under iter t's VALU; optional 8-edge tail.

template<int RS>   // 128 (x / layer0) or 256 (h)
__global__ __launch_bounds__(128) void agg_kernel(
    const unsigned short* __restrict__ h,   // bf16 [N, RS]
    const int* __restrict__ row_start,
    const int2* __restrict__ csr_ec,
    unsigned short* __restrict__ z)         // bf16 [N, RS]
{
    constexpr int LPR = RS / 8;          // lanes per row: 16 or 32
    constexpr int G = 64 / LPR;          // edge-pair groups: 4 or 2
    constexpr int SLOTS = 16 / (2 * G);  // record-pair slots per 16-edge iter: 2 or 4
    constexpr int TSLOTS = SLOTS / 2;    // slots in an 8-edge tail
    int w = threadIdx.x >> 6;
    int lane = threadIdx.x & 63;
    int i = blockIdx.x * 2 + w;
    int g = lane / LPR;
    int sl = lane % LPR;
    int s = row_start[i], e = row_start[i + 1];
    int len = e - s;                 // multiple of 8
    int nfull = len >> 4;
    bool tail = (len & 8) != 0;
    float acc[8] = {};
    const unsigned short* hb = h + sl * 8;

    int4 r[SLOTS];
    #pragma unroll
    for (int u = 0; u < SLOTS; ++u)
        r[u] = *(const int4*)(csr_ec + s + u * (2 * G) + 2 * g);

    int j0 = s;
    for (int t = 0; t < nfull; ++t, j0 += 16) {
        // issue gathers for current records
        uint4 row0[SLOTS], row1[SLOTS];
        #pragma unroll
        for (int u = 0; u < SLOTS; ++u) {
            row0[u] = *(const uint4*)(hb + (size_t)r[u].x * RS);
            row1[u] = *(const uint4*)(hb + (size_t)r[u].z * RS);
        }
        // issue next iteration's record loads (end-pad keeps this in bounds)
        int4 rn[SLOTS];
        #pragma unroll
        for (int u = 0; u < SLOTS; ++u)
            rn[u] = *(const int4*)(csr_ec + (j0 + 16) + u * (2 * G) + 2 * g);
        // compute
        #pragma unroll
        for (int u = 0; u < SLOTS; ++u) {
            unsigned cc = __builtin_amdgcn_perm((unsigned)r[u].y, (unsigned)r[u].w, 0x01000504u);
            const unsigned* p0 = (const unsigned*)&row0[u];
            const unsigned* p1 = (const unsigned*)&row1[u];
            #pragma unroll
            for (int q = 0; q < 4; ++q) {
                unsigned lo = __builtin_amdgcn_perm(p0[q], p1[q], 0x01000504u);
                unsigned hi = __builtin_amdgcn_perm(p0[q], p1[q], 0x03020706u);
                acc[2*q]   = dot2bf(lo, cc, acc[2*q]);
                acc[2*q+1] = dot2bf(hi, cc, acc[2*q+1]);
            }
        }
        #pragma unroll
        for (int u = 0; u < SLOTS; ++u) r[u] = rn[u];
    }
    if (tail) {
        // r[] holds records starting at e-8; use first TSLOTS slots (8 edges)
        uint4 row0[TSLOTS], row1[TSLOTS];
        #pragma unroll
        for (int u = 0; u < TSLOTS; ++u) {
            row0[u] = *(const uint4*)(hb + (size_t)r[u].x * RS);
            row1[u] = *(const uint4*)(hb + (size_t)r[u].z * RS);
        }
        #pragma unroll
        for (int u = 0; u < TSLOTS; ++u) {
            unsigned cc = __builtin_amdgcn_perm((unsigned)r[u].y, (unsigned)r[u].w, 0x01000504u);
            const unsigned* p0 = (const unsigned*)&row0[u];
            const unsigned* p1 = (const unsigned*)&row1[u];
            #pragma unroll
            for (int q = 0; q < 4; ++q) {
                unsigned lo = __builtin_amdgcn_perm(p0[q], p1[q], 0x01000504u);
                unsigned hi = __builtin_amdgcn_perm(p0[q], p1[q], 0x03020706u);
                acc[2*q]   = dot2bf(lo, cc, acc[2*q]);
                acc[2*q+1] = dot2bf(hi, cc, acc[2*q+1]);
            }
        }
    }
    // butterfly-combine across edge groups
    #pragma unroll
    for (int off = LPR; off < 64; off <<= 1)
        #pragma unroll
        for (int q = 0; q < 8; ++q)
            acc[q] += __shfl_xor(acc[q], off, 64);
    if (g == 0) {
        us8 o;
        #pragma unroll
        for (int q = 0; q < 8; ++q) o[q] = f2bf(acc[q]);
        *(us8*)(z + (size_t)i * RS + sl * 8) = o;
    }
}

// ---------------- MFMA GEMM + fused epilogue ----------------
// h' = relu(z@W + b) + (z@W + b); EPI=0: write bf16 h'; EPI=1: LayerNorm -> fp32 out

template<int EPI>
__global__ __launch_bounds__(256) void mfma_gemm_kernel(
    const unsigned short* __restrict__ A, int lda, int aChanOff,
    const unsigned short* __restrict__ Bpack, int ksteps,
    const float* __restrict__ bias, int biasChanStride,
    unsigned short* __restrict__ Cbf,
    float* __restrict__ outF, const float* __restrict__ gamma, const float* __restrict__ beta,
    int M)
{
    int c = blockIdx.y;
    int m0 = blockIdx.x * 64;
    int w = threadIdx.x >> 6, lane = threadIdx.x & 63;
    int arow = m0 + w * 16 + (lane & 15);
    int arow_c = (arow < M) ? arow : (M - 1);
    const unsigned short* Ap = A + (size_t)arow_c * lda + aChanOff * c + (lane >> 4) * 8;
    const unsigned short* Bp = Bpack + ((size_t)c * ksteps * 4) * 512 + (size_t)lane * 8;
    f32x4 acc[4] = {};
    for (int ks = 0; ks < ksteps; ++ks) {
        bf16x8 af = *(const bf16x8*)(Ap + ks * 32);
        const unsigned short* b = Bp + (size_t)ks * 2048;
        #pragma unroll
        for (int n = 0; n < 4; ++n) {
            bf16x8 bfr = *(const bf16x8*)(b + n * 512);
            acc[n] = __builtin_amdgcn_mfma_f32_16x16x32_bf16(af, bfr, acc[n], 0, 0, 0);
        }
    }
    int col = lane & 15;
    int rbase = m0 + w * 16 + (lane >> 4) * 4;
    float hv[4][4];
    #pragma unroll
    for (int n = 0; n < 4; ++n) {
        float bv = bias[c * biasChanStride + n * 16 + col];
        #pragma unroll
        for (int r = 0; r < 4; ++r) {
            float a = acc[n][r] + bv;
            hv[n][r] = (a > 0.f) ? a + a : a;   // relu(a) + a
        }
    }
    if (EPI == 0) {
        #pragma unroll
        for (int n = 0; n < 4; ++n) {
            #pragma unroll
            for (int r = 0; r < 4; ++r) {
                int rr = rbase + r;
                if (rr < M) Cbf[(size_t)rr * D_ALL + c * 64 + n * 16 + col] = f2bf(hv[n][r]);
            }
        }
    } else {
        float sum[4], sq[4];
        #pragma unroll
        for (int r = 0; r < 4; ++r) {
            sum[r] = hv[0][r] + hv[1][r] + hv[2][r] + hv[3][r];
            sq[r] = hv[0][r]*hv[0][r] + hv[1][r]*hv[1][r] + hv[2][r]*hv[2][r] + hv[3][r]*hv[3][r];
        }
        #pragma unroll
        for (int off = 1; off < 16; off <<= 1) {
            #pragma unroll
            for (int r = 0; r < 4; ++r) {
                sum[r] += __shfl_xor(sum[r], off, 64);
                sq[r]  += __shfl_xor(sq[r], off, 64);
            }
        }
        float mu[4], rinv[4];
        #pragma unroll
        for (int r = 0; r < 4; ++r) {
            mu[r] = sum[r] * (1.f / 64.f);
            float var = sq[r] * (1.f / 64.f) - mu[r] * mu[r];
            rinv[r] = rsqrtf(var + 1e-6f);
        }
        #pragma unroll
        for (int n = 0; n < 4; ++n) {
            float gv = gamma[n * 16 + col];
            float bv2 = beta[n * 16 + col];
            #pragma unroll
            for (int r = 0; r < 4; ++r) {
                int rr = rbase + r;
                if (rr < M)
                    outF[(size_t)c * N_NODES * D_H + (size_t)rr * D_H + n * 16 + col] =
                        (hv[n][r] - mu[r]) * rinv[r] * gv + bv2;
            }
        }
    }
}

// ---------------- launch ----------------

extern "C" void kernel_launch(void* const* d_in, const int* in_sizes, int n_in,
                              void* d_out, int out_size, void* d_ws, size_t ws_size,
                              hipStream_t stream) {
    const float* x     = (const float*)d_in[0];
    const int*   edge  = (const int*)d_in[1];
    const float* W0    = (const float*)d_in[3];
    const float* b0    = (const float*)d_in[4];
    const float* Wl    = (const float*)d_in[5];
    const float* bl    = (const float*)d_in[6];
    const float* gamma = (const float*)d_in[7];
    const float* beta  = (const float*)d_in[8];
    float* out = (float*)d_out;

    const int* e_src = edge;            // edge[0]
    const int* e_dst = edge + N_EDGES;  // edge[1]

    char* ws = (char*)d_ws;
    size_t off = 0;
    auto alloc = [&](size_t bytes) -> void* {
        void* p = ws + off;
        off = (off + bytes + 255) & ~(size_t)255;
        return p;
    };
    const int NE_MAX = N_EDGES + 8 * N_NODES + 32;   // x8-padded rows + end pad
    const int NB_SCAN = (N_NODES + 1023) / 1024;     // 49
    int*   deg_cnt   = (int*)  alloc(sizeof(int)   * N_NODES);
    int*   cursor    = (int*)  alloc(sizeof(int)   * N_NODES);
    int*   row_start = (int*)  alloc(sizeof(int)   * (N_NODES + 1));
    int*   bsum      = (int*)  alloc(sizeof(int)   * 64);
    float* dinv      = (float*)alloc(sizeof(float) * N_NODES);
    int2*  csr_ec    = (int2*) alloc(sizeof(int2)  * NE_MAX);
    unsigned short* x_bf  = (unsigned short*)alloc(sizeof(unsigned short) * (size_t)N_NODES * D_IN);
    unsigned short* W0p   = (unsigned short*)alloc(sizeof(unsigned short) * SZ_C * 4 * 4 * 512);
    unsigned short* Wl0p  = (unsigned short*)alloc(sizeof(unsigned short) * SZ_C * 2 * 4 * 512);
    unsigned short* Wl1p  = (unsigned short*)alloc(sizeof(unsigned short) * SZ_C * 2 * 4 * 512);
    unsigned short* zbuf  = (unsigned short*)alloc(sizeof(unsigned short) * (size_t)N_NODES * D_ALL);
    unsigned short* h_bf  = (unsigned short*)alloc(sizeof(unsigned short) * (size_t)N_NODES * D_ALL);

    const int nb_n = (N_NODES + 255) / 256;
    const int nb_e = (N_EDGES + 255) / 256;
    const int n4   = N_NODES * D_IN / 4;             // 1.6M elems / 4

    init_f2bf_kernel<<<(n4 + 255) / 256, 256, 0, stream>>>(x, x_bf, n4, deg_cnt, cursor, N_NODES);
    hist_kernel<<<nb_e, 256, 0, stream>>>(e_dst, deg_cnt, N_EDGES);
    scan_block_kernel<<<NB_SCAN, 1024, 0, stream>>>(deg_cnt, dinv, row_start, bsum, N_NODES);
    scan_tot_kernel<<<1, 64, 0, stream>>>(bsum, NB_SCAN);
    scan_add_kernel<<<NB_SCAN, 1024, 0, stream>>>(bsum, row_start, N_NODES);
    csr_build_kernel<<<nb_e, 256, 0, stream>>>(e_src, e_dst, row_start, cursor, dinv,
                                               csr_ec, N_EDGES);
    self_pad_kernel<<<nb_n, 256, 0, stream>>>(row_start, deg_cnt, dinv, csr_ec, N_NODES);
    {
        dim3 pgrid((SZ_C * 4 * 4 * 512 + 255) / 256, 3);
        pack_all_kernel<<<pgrid, 256, 0, stream>>>(W0, Wl, W0p, Wl0p, Wl1p);
    }

    dim3 ggrid((N_NODES + 63) / 64, SZ_C);
    const int agg_grid = N_NODES / 2;  // 25000 blocks x 128 threads (2 nodes each)

    // layer 0: z = agg(x_bf) [N,128]; h = relures(z@W0 + b0) [N,256]
    agg_kernel<D_IN><<<agg_grid, 128, 0, stream>>>(x_bf, row_start, csr_ec, zbuf);
    mfma_gemm_kernel<0><<<ggrid, 256, 0, stream>>>(zbuf, D_IN, 0, W0p, 4,
                                                   b0, 64, h_bf, nullptr, nullptr, nullptr, N_NODES);
    // layer 1: z = agg(h) [N,256]; h = relures(z@Wl0 + bl0)
    agg_kernel<D_ALL><<<agg_grid, 128, 0, stream>>>(h_bf, row_start, csr_ec, zbuf);
    mfma_gemm_kernel<0><<<ggrid, 256, 0, stream>>>(zbuf, D_ALL, 64, Wl0p, 2,
                                                   bl, 2 * 64, h_bf, nullptr, nullptr, nullptr, N_NODES);
    // layer 2: z = agg(h); out = LN(relures(z@Wl1 + bl1)) -> d_out fp32
    agg_kernel<D_ALL><<<agg_grid, 128, 0, stream>>>(h_bf, row_start, csr_ec, zbuf);
    mfma_gemm_kernel<1><<<ggrid, 256, 0, stream>>>(zbuf, D_ALL, 64, Wl1p, 2,
                                                   bl + 64, 2 * 64, nullptr, out, gamma, beta, N_NODES);
}